// Round 6
// baseline (233.301 us; speedup 1.0000x reference)
//
#include <hip/hip_runtime.h>
#include <hip/hip_fp16.h>

// Problem constants
#define IMGS 2
#define OW 90
#define NP 8100                // 90*90 valid patches
#define HW 96
#define CH_STRIDE 9216
#define IMG_STRIDE 27648
#define KP 192                 // padded row stride in halfs (data to 159; 160..191 zero)
#define MP 8192                // padded patch count
#define ALPHA 0.05f
#define INV_D (1.0f/147.0f)
#define PAD_SENTINEL 60000.0f  // finite fp16 value >> any real (x2-2c) magnitude

typedef _Float16 half8 __attribute__((ext_vector_type(8)));
typedef float floatx4 __attribute__((ext_vector_type(4)));

// async global->LDS, 16B per lane; LDS dest = uniform base + lane*16
#define GLD_LDS16(gp, lp)                                                     \
    __builtin_amdgcn_global_load_lds(                                         \
        (const __attribute__((address_space(1))) void*)(gp),                  \
        (__attribute__((address_space(3))) void*)(lp), 16, 0, 0)

// ws byte offsets
// A matrix = -2*Y with slot147 = 1.0      (fp16 [2][8192][192])
// B matrix =    X with slot147 = x2_i (valid) / 60000 (pad row)
#define XP_OFF   0
#define YP_OFF   (XP_OFF + IMGS*MP*KP*2)
#define N2Y_OFF  (YP_OFF + IMGS*MP*KP*2)        // float [2][8192] (y norms)
#define RMIN_OFF (N2Y_OFF + IMGS*MP*4)          // int-bits float [2][8192]
#define CMIN_OFF (RMIN_OFF + IMGS*MP*4)

// -------- fused build + norms + min-init ----------------------------------
__global__ __launch_bounds__(256) void k_build(const float* __restrict__ x,
                                               const float* __restrict__ y,
                                               char* __restrict__ wsb) {
    int tid = threadIdx.x;
    int hwv = tid >> 5;                      // half-wave 0..7
    int l = tid & 31;
    int grow = blockIdx.x * 8 + hwv;         // 0..32767
    int tensor = grow >> 14;                 // 0 = x(B), 1 = y(A)
    int img = (grow >> 13) & 1;
    int row = grow & (MP - 1);
    const float* src = (tensor ? y : x) + img * IMG_STRIDE;
    int py = row / OW, px = row - py * OW;
    bool rvalid = row < NP;

    float vals[8];
#pragma unroll
    for (int j = 0; j < 8; j++) {
        int k = l * 8 + j;
        float v = 0.0f;
        if (rvalid && k < 147) {
            int c = k / 49;
            int rm = k - c * 49;
            int dy = rm / 7, dx = rm - dy * 7;
            v = src[c * CH_STRIDE + (py + dy) * HW + px + dx];
        }
        vals[j] = (float)(_Float16)v;        // round through fp16 (ref casts first)
    }
    float ss16 = 0.0f;
#pragma unroll
    for (int j = 0; j < 8; j++) ss16 = fmaf(vals[j], vals[j], ss16);
#pragma unroll
    for (int m = 1; m < 32; m <<= 1) ss16 += __shfl_xor(ss16, m, 32);

    if (tensor && l == 0)
        ((float*)(wsb + N2Y_OFF))[img * MP + row] = rvalid ? ss16 : 0.0f;

    half8 h;
#pragma unroll
    for (int j = 0; j < 8; j++) {
        float f = vals[j];
        if (tensor) f *= -2.0f;              // A = -2*Y (exact in fp16)
        h[j] = (_Float16)f;
    }
    if (l == 18) {                           // k = 147 is j=3 of chunk 18
        h[3] = tensor ? (_Float16)1.0f
                      : (rvalid ? (_Float16)ss16 : (_Float16)PAD_SENTINEL);
    }
    if (l < 24) {
        _Float16* dst = (_Float16*)(wsb + (tensor ? YP_OFF : XP_OFF)) +
                        ((size_t)img * MP + row) * KP + l * 8;
        *(half8*)dst = h;
    }
    if (tid < 8) {                           // min-array init (ws is re-poisoned)
        int gi = blockIdx.x * 8 + tid;
        if (gi < IMGS * MP)
            ((int*)(wsb + RMIN_OFF))[gi] = 0x7f800000;
        else
            ((int*)(wsb + CMIN_OFF))[gi - IMGS * MP] = 0x7f800000;
    }
}

// -------- fused GEMM + min reduction: single-barrier full-K structure -----
// LDS holds the ENTIRE K range (160 halfs): c01 = halfs 0..127 (256B rows,
// 16 chunk slots, XOR c^(r&7) -> 2-way free), c2 = halfs 128..159 (64B rows,
// XOR c^(r&3)). One staging burst (20 GLD/thread), ONE barrier, then 5
// uninterrupted K-steps x 16 MFMA. 80KB LDS -> exactly 2 blocks/CU; one
// block computes while the other fills (fill ~1460cyc vs MFMA ~1550cyc).
// PASS 1: rowmin_t = min_i acc             -> global RMIN (raw)
// PASS 2: colmin_i = min_t (r'_t*acc+ay_t) -> global CMIN  (rinv inline)
template <int PASS>
__global__ __launch_bounds__(256, 2) void k_gemm(char* __restrict__ wsb) {
    __shared__ __align__(16) _Float16 As01[128 * 128];
    __shared__ __align__(16) _Float16 Bs01[128 * 128];
    __shared__ __align__(16) _Float16 As2[128 * 32];
    __shared__ __align__(16) _Float16 Bs2[128 * 32];
    int tid = threadIdx.x;
    int lane = tid & 63, w = tid >> 6;
    int wm = (w >> 1) * 64, wn = (w & 1) * 64;
    int quad = lane >> 4, col16 = lane & 15;
    int ntile = blockIdx.x, mtile = blockIdx.y, img = blockIdx.z;

    const _Float16* Amat = (const _Float16*)(wsb + YP_OFF) +
                           ((size_t)img * MP + mtile * 128) * KP;   // -2*Y rows
    const _Float16* Bmat = (const _Float16*)(wsb + XP_OFF) +
                           ((size_t)img * MP + ntile * 128) * KP;   // X rows

    floatx4 acc[4][4];
#pragma unroll
    for (int i = 0; i < 4; i++)
#pragma unroll
        for (int j = 0; j < 4; j++) acc[i][j] = (floatx4){0.f, 0.f, 0.f, 0.f};

    // ---- staging burst: wave w owns rows w*32 .. w*32+31
    {
        int rbase = w * 32;
        int roff = lane >> 4;                // 0..3 (4 rows per GLD)
        int cc = lane & 15;                  // chunk slot 0..15
#pragma unroll
        for (int g = 0; g < 8; g++) {
            int r = rbase + g * 4 + roff;
            int gc = cc ^ (r & 7);           // stored slot cc holds global chunk gc
            GLD_LDS16(Amat + (size_t)r * KP + gc * 8, &As01[(rbase + g * 4) * 128]);
            GLD_LDS16(Bmat + (size_t)r * KP + gc * 8, &Bs01[(rbase + g * 4) * 128]);
        }
        int roff2 = lane >> 2;               // 0..15 (16 rows per GLD)
        int cc2 = lane & 3;                  // chunk slot 0..3
#pragma unroll
        for (int g = 0; g < 2; g++) {
            int r = rbase + g * 16 + roff2;
            int gc = cc2 ^ (r & 3);
            GLD_LDS16(Amat + (size_t)r * KP + 128 + gc * 8, &As2[(rbase + g * 16) * 32]);
            GLD_LDS16(Bmat + (size_t)r * KP + 128 + gc * 8, &Bs2[(rbase + g * 16) * 32]);
        }
    }
    __syncthreads();                          // the ONE barrier (drains vmcnt)

#pragma unroll
    for (int ks = 0; ks < 5; ks++) {
        half8 a[4], b[4];
#pragma unroll
        for (int mi = 0; mi < 4; mi++) {
            int row = wm + mi * 16 + col16;
            a[mi] = (ks < 4)
                ? *(const half8*)(&As01[row * 128 + (((ks * 4 + quad) ^ (row & 7)) * 8)])
                : *(const half8*)(&As2[row * 32 + ((quad ^ (row & 3)) * 8)]);
        }
#pragma unroll
        for (int ni = 0; ni < 4; ni++) {
            int row = wn + ni * 16 + col16;
            b[ni] = (ks < 4)
                ? *(const half8*)(&Bs01[row * 128 + (((ks * 4 + quad) ^ (row & 7)) * 8)])
                : *(const half8*)(&Bs2[row * 32 + ((quad ^ (row & 3)) * 8)]);
        }
#pragma unroll
        for (int mi = 0; mi < 4; mi++)
#pragma unroll
            for (int ni = 0; ni < 4; ni++)
                acc[mi][ni] = __builtin_amdgcn_mfma_f32_16x16x32_f16(
                    a[mi], b[ni], acc[mi][ni], 0, 0, 0);
    }
    __syncthreads();                          // done reading LDS; reuse for epilogue

    if (PASS == 1) {
        int* redmin = (int*)As01;
        if (tid < 128) redmin[tid] = 0x7f800000;
        __syncthreads();
        // C/D layout: col = lane&15, row = quad*4 + reg
#pragma unroll
        for (int mi = 0; mi < 4; mi++)
#pragma unroll
            for (int r = 0; r < 4; r++) {
                int row_l = wm + mi * 16 + quad * 4 + r;
                float best = fminf(fminf(acc[mi][0][r], acc[mi][1][r]),
                                   fminf(acc[mi][2][r], acc[mi][3][r]));
                best = fminf(best, __shfl_xor(best, 1, 16));
                best = fminf(best, __shfl_xor(best, 2, 16));
                best = fminf(best, __shfl_xor(best, 4, 16));
                best = fminf(best, __shfl_xor(best, 8, 16));
                if (col16 == 0) atomicMin(&redmin[row_l], __float_as_int(best));
            }
        __syncthreads();
        if (tid < 128)
            atomicMin((int*)(wsb + RMIN_OFF) + img * MP + mtile * 128 + tid, redmin[tid]);
    } else {
        float* rs = (float*)As01;        // r' per row
        float* ay = (float*)As01 + 128;  // ay per row
        int* colmin = (int*)As01 + 256;
        if (tid < 128) {
            int grow = mtile * 128 + tid;
            float rm = __int_as_float(((const int*)(wsb + RMIN_OFF))[img * MP + grow]);
            float y2 = ((const float*)(wsb + N2Y_OFF))[img * MP + grow];
            float d = (y2 + rm) * INV_D;           // rowmin distance
            float rp = INV_D / (d + ALPHA);        // r' = INV_D * rinv
            bool valid = grow < NP;
            rs[tid] = valid ? rp : 0.0f;
            ay[tid] = valid ? rp * y2 : __builtin_huge_valf();
            colmin[tid] = 0x7f800000;
        }
        __syncthreads();
        float bestni[4] = {1e30f, 1e30f, 1e30f, 1e30f};
#pragma unroll
        for (int mi = 0; mi < 4; mi++)
#pragma unroll
            for (int r = 0; r < 4; r++) {
                int row_l = wm + mi * 16 + quad * 4 + r;
                float rr = rs[row_l];    // broadcast within quad-group
                float aa = ay[row_l];
#pragma unroll
                for (int ni = 0; ni < 4; ni++)
                    bestni[ni] = fminf(bestni[ni], fmaf(rr, acc[mi][ni][r], aa));
            }
#pragma unroll
        for (int ni = 0; ni < 4; ni++) {
            float best = bestni[ni];
            best = fminf(best, __shfl_xor(best, 16, 64));
            best = fminf(best, __shfl_xor(best, 32, 64));
            if (quad == 0)
                atomicMin(&colmin[wn + ni * 16 + col16], __float_as_int(best));
        }
        __syncthreads();
        if (tid < 128)
            atomicMin((int*)(wsb + CMIN_OFF) + img * MP + ntile * 128 + tid, colmin[tid]);
    }
}

// -------- finalize: mean over inputs, mean over images --------------------
__global__ __launch_bounds__(256) void k_final(const char* __restrict__ wsb,
                                               float* __restrict__ out) {
    __shared__ float red[256];
    int tid = threadIdx.x;
    const int* cm = (const int*)(wsb + CMIN_OFF);
    float s = 0.0f;
    for (int i = tid; i < NP; i += 256) {
        s += __int_as_float(cm[i]);
        s += __int_as_float(cm[MP + i]);
    }
    red[tid] = s;
    __syncthreads();
    for (int st = 128; st > 0; st >>= 1) {
        if (tid < st) red[tid] += red[tid + st];
        __syncthreads();
    }
    if (tid == 0) out[0] = red[0] * (0.5f / NP);
}

extern "C" void kernel_launch(void* const* d_in, const int* in_sizes, int n_in,
                              void* d_out, int out_size, void* d_ws, size_t ws_size,
                              hipStream_t stream) {
    const float* x = (const float*)d_in[0];
    const float* y = (const float*)d_in[1];
    char* wsb = (char*)d_ws;
    float* out = (float*)d_out;

    k_build<<<4096, 256, 0, stream>>>(x, y, wsb);
    k_gemm<1><<<dim3(64, 64, IMGS), 256, 0, stream>>>(wsb);
    k_gemm<2><<<dim3(64, 64, IMGS), 256, 0, stream>>>(wsb);
    k_final<<<1, 256, 0, stream>>>(wsb, out);
}

// Round 7
// 170.592 us; speedup vs baseline: 1.3676x; 1.3676x over previous
//
#include <hip/hip_runtime.h>
#include <hip/hip_fp16.h>

// Problem constants
#define IMGS 2
#define OW 90
#define NP 8100                // 90*90 valid patches
#define HW 96
#define CH_STRIDE 9216
#define IMG_STRIDE 27648
#define KP 192                 // padded row stride in halfs (data to 159; rest zero)
#define MP 8192                // padded patch count
#define ALPHA 0.05f
#define INV_D (1.0f/147.0f)
#define PAD_SENTINEL 60000.0f  // finite fp16 value >> any real (x2-2c) magnitude

typedef _Float16 half8 __attribute__((ext_vector_type(8)));
typedef float floatx4 __attribute__((ext_vector_type(4)));

// async global->LDS, 16B per lane; LDS dest = uniform base + lane*16
#define GLD_LDS16(gp, lp)                                                     \
    __builtin_amdgcn_global_load_lds(                                         \
        (const __attribute__((address_space(1))) void*)(gp),                  \
        (__attribute__((address_space(3))) void*)(lp), 16, 0, 0)

// ws byte offsets
// A matrix = -2*Y with slot147 = 1.0      (fp16 [2][8192][192])
// B matrix =    X with slot147 = x2_i (valid) / 60000 (pad row)
#define XP_OFF   0
#define YP_OFF   (XP_OFF + IMGS*MP*KP*2)
#define N2Y_OFF  (YP_OFF + IMGS*MP*KP*2)        // float [2][8192] (y norms)
#define RMIN_OFF (N2Y_OFF + IMGS*MP*4)          // int-bits float [2][8192]
#define RINV_OFF (RMIN_OFF + IMGS*MP*4)         // r' = INV_D*rinv (0 for pad rows)
#define AY_OFF   (RINV_OFF + IMGS*MP*4)         // ay = r'*y2 (+inf for pad rows)
#define CMIN_OFF (AY_OFF + IMGS*MP*4)

// -------- fused build + norms + min-init ----------------------------------
__global__ __launch_bounds__(256) void k_build(const float* __restrict__ x,
                                               const float* __restrict__ y,
                                               char* __restrict__ wsb) {
    int tid = threadIdx.x;
    int hwv = tid >> 5;                      // half-wave 0..7
    int l = tid & 31;
    int grow = blockIdx.x * 8 + hwv;         // 0..32767
    int tensor = grow >> 14;                 // 0 = x(B), 1 = y(A)
    int img = (grow >> 13) & 1;
    int row = grow & (MP - 1);
    const float* src = (tensor ? y : x) + img * IMG_STRIDE;
    int py = row / OW, px = row - py * OW;
    bool rvalid = row < NP;

    float vals[8];
#pragma unroll
    for (int j = 0; j < 8; j++) {
        int k = l * 8 + j;
        float v = 0.0f;
        if (rvalid && k < 147) {
            int c = k / 49;
            int rm = k - c * 49;
            int dy = rm / 7, dx = rm - dy * 7;
            v = src[c * CH_STRIDE + (py + dy) * HW + px + dx];
        }
        vals[j] = (float)(_Float16)v;        // round through fp16 (ref casts first)
    }
    float ss16 = 0.0f;
#pragma unroll
    for (int j = 0; j < 8; j++) ss16 = fmaf(vals[j], vals[j], ss16);
#pragma unroll
    for (int m = 1; m < 32; m <<= 1) ss16 += __shfl_xor(ss16, m, 32);

    if (tensor && l == 0)
        ((float*)(wsb + N2Y_OFF))[img * MP + row] = rvalid ? ss16 : 0.0f;

    half8 h;
#pragma unroll
    for (int j = 0; j < 8; j++) {
        float f = vals[j];
        if (tensor) f *= -2.0f;              // A = -2*Y (exact in fp16)
        h[j] = (_Float16)f;
    }
    if (l == 18) {                           // k = 147 is j=3 of chunk 18
        h[3] = tensor ? (_Float16)1.0f
                      : (rvalid ? (_Float16)ss16 : (_Float16)PAD_SENTINEL);
    }
    if (l < 24) {
        _Float16* dst = (_Float16*)(wsb + (tensor ? YP_OFF : XP_OFF)) +
                        ((size_t)img * MP + row) * KP + l * 8;
        *(half8*)dst = h;
    }
    if (tid < 8) {                           // min-array init (ws is re-poisoned)
        int gi = blockIdx.x * 8 + tid;
        if (gi < IMGS * MP)
            ((int*)(wsb + RMIN_OFF))[gi] = 0x7f800000;
        else
            ((int*)(wsb + CMIN_OFF))[gi - IMGS * MP] = 0x7f800000;
    }
}

// -------- resident-operand streaming GEMM + register min reduction --------
// Block owns a resident 128-row tile whose 20 MFMA fragments live in VGPRs
// for the whole kernel; 16 counter-tiles stream through double-buffered LDS
// (40KB/buf: region1 = K-chunks 0..15 swizzle c^(r&7), region2 = K-chunks
// 16..19 swizzle c^((r>>1)&3); both 2-way on b128 reads -> free).
// Prefetch for step s+1 is issued AFTER the step-s barrier, so its vmcnt
// drain (next barrier) lands a full ~1550-cyc compute phase later.
// PASS 1: resident = A (-2Y, mtile), stream B (X). rowmin in regs.
// PASS 2: resident = B (X, ntile), stream A. colmin in regs (r'*acc+ay).
template <int PASS>
__global__ __launch_bounds__(256, 2) void k_gemm(char* __restrict__ wsb) {
    __shared__ __align__(16) _Float16 B0r1[128 * 128];   // 32 KB
    __shared__ __align__(16) _Float16 B0r2[128 * 32];    //  8 KB
    __shared__ __align__(16) _Float16 B1r1[128 * 128];
    __shared__ __align__(16) _Float16 B1r2[128 * 32];
    int tid = threadIdx.x;
    int lane = tid & 63, w = tid >> 6;
    int wm = (w >> 1) * 64, wn = (w & 1) * 64;
    int quad = lane >> 4, col16 = lane & 15;
    int q = blockIdx.x;                      // quarter: 16 streamed tiles
    int rtile = blockIdx.y;                  // resident tile index
    int img = blockIdx.z;

    const _Float16* Res = (const _Float16*)(wsb + (PASS == 1 ? YP_OFF : XP_OFF)) +
                          ((size_t)img * MP + rtile * 128) * KP;
    const _Float16* Str = (const _Float16*)(wsb + (PASS == 1 ? XP_OFF : YP_OFF)) +
                          (size_t)img * MP * KP;

    // ---- staging: wave w stages rows w*32..w*32+31 of a 128x160h tile ----
    int roff1 = lane >> 4, cc1 = lane & 15;  // region1: 4 rows/GLD
    int roff2 = lane >> 2, cc2 = lane & 3;   // region2: 16 rows/GLD
#define STAGE(Mat, R1, R2)                                                     \
    {                                                                          \
        int rbase = w * 32;                                                    \
        _Pragma("unroll") for (int g = 0; g < 8; g++) {                        \
            int r = rbase + g * 4 + roff1;                                     \
            int gc = cc1 ^ (r & 7);                                            \
            GLD_LDS16((Mat) + (size_t)r * KP + gc * 8, &(R1)[(rbase + g * 4) * 128]); \
        }                                                                      \
        _Pragma("unroll") for (int g = 0; g < 2; g++) {                        \
            int r = rbase + g * 16 + roff2;                                    \
            int gc = cc2 ^ ((r >> 1) & 3);                                     \
            GLD_LDS16((Mat) + (size_t)r * KP + 128 + gc * 8, &(R2)[(rbase + g * 16) * 32]); \
        }                                                                      \
    }

#define READFRAG(R1, R2, row, ks)                                              \
    ((ks) < 4 ? *(const half8*)(&(R1)[(row) * 128 + ((((ks) * 4 + quad) ^ ((row) & 7)) * 8)]) \
              : *(const half8*)(&(R2)[(row) * 32 + ((quad ^ (((row) >> 1) & 3)) * 8)]))

    // ---- prologue: resident tile -> LDS -> registers ----
    STAGE(Res, B0r1, B0r2);
    __syncthreads();
    half8 rf[4][5];
    int rrow0 = (PASS == 1) ? wm : wn;
#pragma unroll
    for (int i = 0; i < 4; i++)
#pragma unroll
        for (int c = 0; c < 5; c++)
            rf[i][c] = READFRAG(B0r1, B0r2, rrow0 + i * 16 + col16, c);
    __syncthreads();                         // all waves done reading buf0
    STAGE(Str + (size_t)(q * 16) * 128 * KP, B0r1, B0r2);   // step 0 -> buf0

    float rmin[4][4];                        // PASS1: per-(mi,r) row mins
    float cmin[4];                           // PASS2: per-ni col mins
#pragma unroll
    for (int i = 0; i < 4; i++) {
        cmin[i] = 1e30f;
#pragma unroll
        for (int j = 0; j < 4; j++) rmin[i][j] = 1e30f;
    }
    int srow0 = (PASS == 1) ? wn : wm;
    const float* RIp = (const float*)(wsb + RINV_OFF) + img * MP;
    const float* AYp = (const float*)(wsb + AY_OFF) + img * MP;

    for (int s = 0; s < 16; s++) {
        __syncthreads();                     // step-s data ready; buf reads of s-1 done
        const _Float16* R1 = (s & 1) ? B1r1 : B0r1;
        const _Float16* R2 = (s & 1) ? B1r2 : B0r2;
        if (s < 15) {                        // prefetch s+1 into the other buffer
            _Float16* W1 = (s & 1) ? B0r1 : B1r1;
            _Float16* W2 = (s & 1) ? B0r2 : B1r2;
            const _Float16* M = Str + (size_t)(q * 16 + s + 1) * 128 * KP;
            STAGE(M, W1, W2);
        }
        float rr[4][4], aa[4][4];
        if (PASS == 2) {                     // r'/ay for streamed rows (L2 broadcast)
            int rgb = (q * 16 + s) * 128 + wm + quad * 4;
#pragma unroll
            for (int mi = 0; mi < 4; mi++)
#pragma unroll
                for (int r = 0; r < 4; r++) {
                    rr[mi][r] = RIp[rgb + mi * 16 + r];
                    aa[mi][r] = AYp[rgb + mi * 16 + r];
                }
        }
        floatx4 acc[4][4];
#pragma unroll
        for (int i = 0; i < 4; i++)
#pragma unroll
            for (int j = 0; j < 4; j++) acc[i][j] = (floatx4){0.f, 0.f, 0.f, 0.f};
#pragma unroll
        for (int ks = 0; ks < 5; ks++) {
            half8 sf[4];
#pragma unroll
            for (int i = 0; i < 4; i++)
                sf[i] = READFRAG(R1, R2, srow0 + i * 16 + col16, ks);
#pragma unroll
            for (int mi = 0; mi < 4; mi++)
#pragma unroll
                for (int ni = 0; ni < 4; ni++)
                    acc[mi][ni] = __builtin_amdgcn_mfma_f32_16x16x32_f16(
                        (PASS == 1) ? rf[mi][ks] : sf[mi],
                        (PASS == 1) ? sf[ni] : rf[ni][ks],
                        acc[mi][ni], 0, 0, 0);
        }
        // fold into register mins (pad cols/rows auto-masked by sentinel / ay=inf)
        if (PASS == 1) {
#pragma unroll
            for (int mi = 0; mi < 4; mi++)
#pragma unroll
                for (int r = 0; r < 4; r++) {
                    float m4 = fminf(fminf(acc[mi][0][r], acc[mi][1][r]),
                                     fminf(acc[mi][2][r], acc[mi][3][r]));
                    rmin[mi][r] = fminf(rmin[mi][r], m4);
                }
        } else {
#pragma unroll
            for (int mi = 0; mi < 4; mi++)
#pragma unroll
                for (int r = 0; r < 4; r++) {
#pragma unroll
                    for (int ni = 0; ni < 4; ni++)
                        cmin[ni] = fminf(cmin[ni],
                                         fmaf(rr[mi][r], acc[mi][ni][r], aa[mi][r]));
                }
        }
    }

    // ---- final reduction: shuffle + one global atomicMin per row/col -----
    if (PASS == 1) {
#pragma unroll
        for (int mi = 0; mi < 4; mi++)
#pragma unroll
            for (int r = 0; r < 4; r++) {
                float best = rmin[mi][r];
                best = fminf(best, __shfl_xor(best, 1, 16));
                best = fminf(best, __shfl_xor(best, 2, 16));
                best = fminf(best, __shfl_xor(best, 4, 16));
                best = fminf(best, __shfl_xor(best, 8, 16));
                int rg = rtile * 128 + wm + mi * 16 + quad * 4 + r;
                if (col16 == 0 && rg < NP)
                    atomicMin((int*)(wsb + RMIN_OFF) + img * MP + rg,
                              __float_as_int(best));
            }
    } else {
#pragma unroll
        for (int ni = 0; ni < 4; ni++) {
            float best = cmin[ni];
            best = fminf(best, __shfl_xor(best, 16, 64));
            best = fminf(best, __shfl_xor(best, 32, 64));
            if (quad == 0)
                atomicMin((int*)(wsb + CMIN_OFF) + img * MP +
                              rtile * 128 + wn + ni * 16 + col16,
                          __float_as_int(best));
        }
    }
}

// -------- rinv: finish rowmin, bake constants for pass 2 ------------------
__global__ __launch_bounds__(256) void k_rinv(char* __restrict__ wsb) {
    int gid = blockIdx.x * 256 + threadIdx.x;      // 2*8192
    float rm = __int_as_float(((const int*)(wsb + RMIN_OFF))[gid]);
    float y2 = ((const float*)(wsb + N2Y_OFF))[gid];
    float d = (y2 + rm) * INV_D;                   // rowmin distance
    float rp = INV_D / (d + ALPHA);                // r' = INV_D * rinv
    bool valid = (gid & (MP - 1)) < NP;
    ((float*)(wsb + RINV_OFF))[gid] = valid ? rp : 0.0f;
    ((float*)(wsb + AY_OFF))[gid] = valid ? rp * y2 : __builtin_huge_valf();
}

// -------- finalize: mean over inputs, mean over images --------------------
__global__ __launch_bounds__(256) void k_final(const char* __restrict__ wsb,
                                               float* __restrict__ out) {
    __shared__ float red[256];
    int tid = threadIdx.x;
    const int* cm = (const int*)(wsb + CMIN_OFF);
    float s = 0.0f;
    for (int i = tid; i < NP; i += 256) {
        s += __int_as_float(cm[i]);
        s += __int_as_float(cm[MP + i]);
    }
    red[tid] = s;
    __syncthreads();
    for (int st = 128; st > 0; st >>= 1) {
        if (tid < st) red[tid] += red[tid + st];
        __syncthreads();
    }
    if (tid == 0) out[0] = red[0] * (0.5f / NP);
}

extern "C" void kernel_launch(void* const* d_in, const int* in_sizes, int n_in,
                              void* d_out, int out_size, void* d_ws, size_t ws_size,
                              hipStream_t stream) {
    const float* x = (const float*)d_in[0];
    const float* y = (const float*)d_in[1];
    char* wsb = (char*)d_ws;
    float* out = (float*)d_out;

    k_build<<<4096, 256, 0, stream>>>(x, y, wsb);
    k_gemm<1><<<dim3(4, 64, IMGS), 256, 0, stream>>>(wsb);
    k_rinv<<<(IMGS * MP) / 256, 256, 0, stream>>>(wsb);
    k_gemm<2><<<dim3(4, 64, IMGS), 256, 0, stream>>>(wsb);
    k_final<<<1, 256, 0, stream>>>(wsb, out);
}